// Round 5
// baseline (44.977 us; speedup 1.0000x reference)
//
#include <hip/hip_runtime.h>

#define WINDOW 10
#define TDIM 4096
#define TVALID (TDIM - WINDOW)   // 4086 valid outputs per row

typedef __attribute__((ext_vector_type(8)))  short bf16x8;   // MFMA operand (4 VGPRs)
typedef __attribute__((ext_vector_type(8)))  __bf16 bfv8;
typedef __attribute__((ext_vector_type(8)))  float f32x8;
typedef __attribute__((ext_vector_type(16))) float f32x16;
typedef __attribute__((ext_vector_type(2)))  float f32x2;
typedef float f32x4u __attribute__((ext_vector_type(4), aligned(4)));

static __device__ __forceinline__ short f2bf(float f) {
  return (short)__builtin_bit_cast(unsigned short, (__bf16)f);   // RNE cvt
}

static __device__ __forceinline__ f32x8 ld8(const float* __restrict__ p) {
  f32x4u a = *(const f32x4u*)p;
  f32x4u b = *(const f32x4u*)(p + 4);
  f32x8 f;
  f[0] = a[0]; f[1] = a[1]; f[2] = a[2]; f[3] = a[3];
  f[4] = b[0]; f[5] = b[1]; f[6] = b[2]; f[7] = b[3];
  return f;
}

static __device__ __forceinline__ f32x8 ld8c(const float* __restrict__ rowp, int base) {
  f32x8 f;
  #pragma unroll
  for (int j = 0; j < 8; ++j) {
    int idx = base + j; idx = idx < TDIM - 1 ? idx : TDIM - 1;   // clamp: OOB slots are don't-cares
    f[j] = rowp[idx];
  }
  return f;
}

static __device__ __forceinline__ bf16x8 packbf(f32x8 f, bool g1) {
  f[2] = g1 ? 1.0f : f[2];          // bias column at k-slot 10
  return __builtin_bit_cast(bf16x8, __builtin_convertvector(f, bfv8));  // 4x v_cvt_pk_bf16_f32
}

// layer-2 relu-dot over this lane's 16 channels, packed fp32
static __device__ __forceinline__ float l2dot(const f32x16& acc, const f32x2* __restrict__ w2p) {
  const f32x2 z2 = {0.f, 0.f};
  f32x2 s0 = z2, s1 = z2;
  #pragma unroll
  for (int j = 0; j < 8; j += 2) {
    f32x2 a = {acc[2*j],     acc[2*j + 1]};
    f32x2 b = {acc[2*j + 2], acc[2*j + 3]};
    s0 = __builtin_elementwise_fma(__builtin_elementwise_max(a, z2), w2p[j],     s0);
    s1 = __builtin_elementwise_fma(__builtin_elementwise_max(b, z2), w2p[j + 1], s1);
  }
  f32x2 s = s0 + s1;
  return s[0] + s[1];
}

// lanes<32 get Pe.lo+Pe.hi, lanes>=32 get Po.lo+Po.hi — one swap + one add
static __device__ __forceinline__ float combine_halves(float Pe, float Po, int lid) {
#if __has_builtin(__builtin_amdgcn_permlane32_swap)
  auto r = __builtin_amdgcn_permlane32_swap(
      __builtin_bit_cast(unsigned, Pe), __builtin_bit_cast(unsigned, Po), false, false);
  return __builtin_bit_cast(float, (unsigned)r[0]) + __builtin_bit_cast(float, (unsigned)r[1]);
#else
  Pe += __shfl_xor(Pe, 32, 64);
  Po += __shfl_xor(Po, 32, 64);
  return (lid < 32) ? Pe : Po;
#endif
}

static __device__ __forceinline__ float half_sigmoid(float z) {
  float e = __expf(-z);
#if __has_builtin(__builtin_amdgcn_rcpf)
  return 0.5f * __builtin_amdgcn_rcpf(1.0f + e);   // single v_rcp_f32
#else
  return 0.5f / (1.0f + e);
#endif
}

__global__ __launch_bounds__(256) void hurst_mfma5(
    const float* __restrict__ ret, const float* __restrict__ W1,
    const float* __restrict__ b1,  const float* __restrict__ W2,
    const float* __restrict__ b2,  float* __restrict__ out) {
  const int lid = threadIdx.x & 63;
  const int wv  = threadIdx.x >> 6;      // wave = 1024-wide t-segment
  const int n   = lid & 31;
  const int g   = lid >> 5;
  const bool g1 = (g == 1);

  // A fragment: W1 rows, b1 fused at k-slot 10 (B supplies 1.0 there); k=11..15 zero
  bf16x8 af;
  if (!g1) {
    #pragma unroll
    for (int j = 0; j < 8; ++j) af[j] = f2bf(W1[n * WINDOW + j]);
  } else {
    af[0] = f2bf(W1[n * WINDOW + 8]);
    af[1] = f2bf(W1[n * WINDOW + 9]);
    af[2] = f2bf(b1[n]);
    #pragma unroll
    for (int j = 3; j < 8; ++j) af[j] = 0;   // B k=11..15 are don't-cares
  }

  // layer-2 weights per acc reg pair: D row m = (r&3)+8*(r>>2)+4*g (HW-verified map)
  f32x2 w2p[8];
  #pragma unroll
  for (int j = 0; j < 8; ++j) {
    w2p[j][0] = W2[((2*j)   & 3) + 8 * ((2*j)   >> 2) + 4 * g];
    w2p[j][1] = W2[((2*j+1) & 3) + 8 * ((2*j+1) >> 2) + 4 * g];
  }
  const float b2c = b2[0];

  const int row = blockIdx.x;
  const float* __restrict__ rowp = ret + (size_t)row * TDIM;
  float* __restrict__ orow = out + (size_t)row * TDIM;
  const int seg   = wv * 1024;
  const int lbase = n + 8 * g;
  const float* __restrict__ lanep = rowp + seg + lbase;

  f32x8 fe = ld8(lanep);                 // tile 0
  f32x8 fo = ld8(lanep + 32);            // tile 1
  float y;

  // One tile-pair: 2 MFMAs with single transient acc each; prefetch next pair
  // between MFMA issue and l2dot so VMEM latency hides under compute.
#define PAIR(P, PRE, MASK)                                                     \
  {                                                                            \
    bf16x8 bve = packbf(fe, g1);                                               \
    f32x16 acce = {};                                                          \
    acce = __builtin_amdgcn_mfma_f32_32x32x16_bf16(af, bve, acce, 0, 0, 0);    \
    if (PRE) fe = ld8(lanep + (2*(P)+2) * 32);                                 \
    float Pe = l2dot(acce, w2p);                                               \
    bf16x8 bvo = packbf(fo, g1);                                               \
    f32x16 acco = {};                                                          \
    acco = __builtin_amdgcn_mfma_f32_32x32x16_bf16(af, bvo, acco, 0, 0, 0);    \
    if (PRE) fo = ld8(lanep + (2*(P)+3) * 32);                                 \
    float Po = l2dot(acco, w2p);                                               \
    const float q = combine_halves(Pe, Po, lid);                               \
    y = half_sigmoid(q + b2c);                                                 \
    const int t = seg + (P) * 64 + lid;                                        \
    if (!(MASK) || t < TVALID) orow[WINDOW + t] = y;                           \
  }

  PAIR(0, true, false)
  if (wv == 0) {                          // head broadcast, once per block
    const float y0 = __shfl(y, 0, 64);
    if (lid < WINDOW) orow[lid] = y0;
  }

  #pragma unroll
  for (int p = 1; p <= 13; ++p) PAIR(p, true, false)

  { // p = 14 (tiles 28,29); prefetch tiles 30,31 — clamp tile 31 for wv==3
    bf16x8 bve = packbf(fe, g1);
    f32x16 acce = {};
    acce = __builtin_amdgcn_mfma_f32_32x32x16_bf16(af, bve, acce, 0, 0, 0);
    fe = ld8(lanep + 30 * 32);
    float Pe = l2dot(acce, w2p);
    bf16x8 bvo = packbf(fo, g1);
    f32x16 acco = {};
    acco = __builtin_amdgcn_mfma_f32_32x32x16_bf16(af, bvo, acco, 0, 0, 0);
    if (wv == 3) fo = ld8c(rowp, seg + 31 * 32 + lbase);
    else         fo = ld8(lanep + 31 * 32);
    float Po = l2dot(acco, w2p);
    const float q = combine_halves(Pe, Po, lid);
    y = half_sigmoid(q + b2c);
    orow[WINDOW + seg + 14 * 64 + lid] = y;
  }

  PAIR(15, false, true)                   // tiles 30,31; masked store (wv3 tail)
#undef PAIR
}

extern "C" void kernel_launch(void* const* d_in, const int* in_sizes, int n_in,
                              void* d_out, int out_size, void* d_ws, size_t ws_size,
                              hipStream_t stream) {
  const float* ret = (const float*)d_in[0];
  const float* W1  = (const float*)d_in[1];
  const float* b1  = (const float*)d_in[2];
  const float* W2  = (const float*)d_in[3];
  const float* b2  = (const float*)d_in[4];
  float* out = (float*)d_out;

  const int B = in_sizes[0] / TDIM;      // 2048
  dim3 block(256);                       // 4 waves x 1024-wide segments
  dim3 grid(B);
  hipLaunchKernelGGL(hurst_mfma5, grid, block, 0, stream,
                     ret, W1, b1, W2, b2, out);
}